// Round 1
// baseline (365.039 us; speedup 1.0000x reference)
//
#include <hip/hip_runtime.h>
#include <hip/hip_bf16.h>

#define D_MODEL 1280
#define NUM_EXPERTS 20
#define HEAD_DIM 64
#define SEQ 1024
#define BATCH 4
#define BS_TOK 4096
#define QKV_N 192

typedef __attribute__((ext_vector_type(8))) short short8;
typedef __attribute__((ext_vector_type(4))) float f32x4;
typedef __hip_bfloat16 bf16;

static __device__ __forceinline__ void gload_lds16(const void* g, void* l) {
  __builtin_amdgcn_global_load_lds((const __attribute__((address_space(1))) void*)g,
                                   (__attribute__((address_space(3))) void*)l, 16, 0, 0);
}

// ---------------- router gates + x -> bf16 ----------------
__global__ __launch_bounds__(256) void k_gates(const float* __restrict__ x,
    const float* __restrict__ rw, const float* __restrict__ rb,
    float* __restrict__ gates, bf16* __restrict__ xb)
{
  __shared__ float xs[D_MODEL];
  __shared__ float logits[NUM_EXPERTS];
  const int row = blockIdx.x;
  const float* xr = x + (size_t)row * D_MODEL;
  bf16* xbr = xb + (size_t)row * D_MODEL;
  for (int i = threadIdx.x; i < D_MODEL; i += 256) {
    float v = xr[i];
    xs[i] = v;
    xbr[i] = __float2bfloat16(v);
  }
  __syncthreads();
  const int wid = threadIdx.x >> 6, lane = threadIdx.x & 63;
  for (int e = wid; e < NUM_EXPERTS; e += 4) {
    float s = 0.f;
    for (int d = lane; d < D_MODEL; d += 64)
      s += xs[d] * rw[d * NUM_EXPERTS + e];
    for (int m = 32; m >= 1; m >>= 1) s += __shfl_xor(s, m);
    if (lane == 0) logits[e] = s + rb[e];
  }
  __syncthreads();
  if (threadIdx.x < 32) {
    float v = (threadIdx.x < NUM_EXPERTS) ? logits[threadIdx.x] : -1e30f;
    float mx = v;
    for (int m = 16; m >= 1; m >>= 1) mx = fmaxf(mx, __shfl_xor(mx, m, 32));
    float p = (threadIdx.x < NUM_EXPERTS) ? __expf(v - mx) : 0.f;
    float sum = p;
    for (int m = 16; m >= 1; m >>= 1) sum += __shfl_xor(sum, m, 32);
    if (threadIdx.x < NUM_EXPERTS)
      gates[(size_t)row * NUM_EXPERTS + threadIdx.x] = p / sum;
  }
}

// ---------------- f32 [batch][R][C] -> bf16 [batch][C][R] ----------------
__global__ __launch_bounds__(256) void k_transpose(const float* __restrict__ in,
    bf16* __restrict__ out, int R, int C)
{
  __shared__ float tile[32][33];
  const size_t bo = (size_t)blockIdx.z * R * C;
  const int c0 = blockIdx.x * 32, r0 = blockIdx.y * 32;
  const int tx = threadIdx.x, ty = threadIdx.y;  // block (32,8)
  #pragma unroll
  for (int i = 0; i < 4; ++i)
    tile[ty + 8*i][tx] = in[bo + (size_t)(r0 + ty + 8*i) * C + (c0 + tx)];
  __syncthreads();
  #pragma unroll
  for (int i = 0; i < 4; ++i)
    out[bo + (size_t)(c0 + ty + 8*i) * R + (r0 + tx)] =
        __float2bfloat16(tile[tx][ty + 8*i]);
}

// ---------------- bf16 MFMA GEMM: C[e] = A @ B[e]^T + bias ----------------
// A [M,K] row-major bf16; BT [batch][N,K] row-major bf16; bias [batch][N] f32
// grid (M/128, N/64, batch), 256 threads (4 waves, 2x2 wave grid, 64x32 each)
template<bool OUT_BF16>
__global__ __launch_bounds__(256) void k_gemm(
    const bf16* __restrict__ A, const bf16* __restrict__ BT,
    const float* __restrict__ bias, void* __restrict__ C,
    int M, int N, int K)
{
  __shared__ __align__(16) bf16 As[128 * 64];
  __shared__ __align__(16) bf16 Bs[64 * 64];
  const int e = blockIdx.z;
  const int m0 = blockIdx.x * 128, n0 = blockIdx.y * 64;
  const int tid = threadIdx.x, wid = tid >> 6, lane = tid & 63;
  const int wr = wid >> 1, wc = wid & 1;
  const int fr = lane & 15, fg = lane >> 4;
  const bf16* Be = BT + (size_t)e * N * K;
  f32x4 acc[4][2] = {};
  for (int k0 = 0; k0 < K; k0 += 64) {
    #pragma unroll
    for (int p = 0; p < 4; ++p) {
      int eidx = ((p*4 + wid)*64 + lane) * 8;
      int row = eidx >> 6, col = eidx & 63;
      gload_lds16(A + (size_t)(m0 + row)*K + k0 + col, As + eidx);
    }
    #pragma unroll
    for (int p = 0; p < 2; ++p) {
      int eidx = ((p*4 + wid)*64 + lane) * 8;
      int row = eidx >> 6, col = eidx & 63;
      gload_lds16(Be + (size_t)(n0 + row)*K + k0 + col, Bs + eidx);
    }
    __syncthreads();
    short8 af[2][4], bfr[2][2];
    #pragma unroll
    for (int kk = 0; kk < 2; ++kk) {
      #pragma unroll
      for (int mi = 0; mi < 4; ++mi)
        af[kk][mi] = *(const short8*)(As + (wr*64 + mi*16 + fr)*64 + kk*32 + fg*8);
      #pragma unroll
      for (int ni = 0; ni < 2; ++ni)
        bfr[kk][ni] = *(const short8*)(Bs + (wc*32 + ni*16 + fr)*64 + kk*32 + fg*8);
    }
    #pragma unroll
    for (int kk = 0; kk < 2; ++kk) {
      #pragma unroll
      for (int mi = 0; mi < 4; ++mi) {
        #pragma unroll
        for (int ni = 0; ni < 2; ++ni)
          acc[mi][ni] = __builtin_amdgcn_mfma_f32_16x16x32_bf16(
              af[kk][mi], bfr[kk][ni], acc[mi][ni], 0, 0, 0);
      }
    }
    __syncthreads();
  }
  #pragma unroll
  for (int mi = 0; mi < 4; ++mi) {
    const int gr = m0 + wr*64 + mi*16 + fg*4;
    #pragma unroll
    for (int ni = 0; ni < 2; ++ni) {
      const int gc = n0 + wc*32 + ni*16 + fr;
      const float bv = bias[(size_t)e * N + gc];
      #pragma unroll
      for (int r = 0; r < 4; ++r) {
        float v = acc[mi][ni][r] + bv;
        size_t off = ((size_t)e * M + gr + r) * N + gc;
        if constexpr (OUT_BF16) ((bf16*)C)[off] = __float2bfloat16(v);
        else                    ((float*)C)[off] = v;
      }
    }
  }
}

// ---------------- flash attention per (qtile, b, e) ----------------
// qkv [E][BS_TOK][192] bf16 (q|k|v), gates [BS_TOK][E] f32
// out: combined [BS_TOK][1280] bf16 (slice e*64)
__global__ __launch_bounds__(256) void k_attn(
    const bf16* __restrict__ qkv, const float* __restrict__ gates,
    bf16* __restrict__ combined)
{
  __shared__ __align__(16) bf16 Ks[64 * 64];   // [key][h]
  __shared__ __align__(16) bf16 VTs[64 * 64];  // [h][key]
  __shared__ __align__(16) bf16 Ps[4][16 * 64];// per-wave P [q16][key64]
  const int e = blockIdx.z, b = blockIdx.y, s0 = blockIdx.x * 64;
  const int tid = threadIdx.x, wid = tid >> 6, lane = tid & 63;
  const int fr = lane & 15, fg = lane >> 4;
  const bf16* base = qkv + ((size_t)e * BS_TOK + b * SEQ) * QKV_N;
  short8 qf[2];
  #pragma unroll
  for (int kk = 0; kk < 2; ++kk)
    qf[kk] = *(const short8*)(base + (size_t)(s0 + wid*16 + fr) * QKV_N + kk*32 + fg*8);
  f32x4 o[4] = {};
  float Mr[4], Lr[4];
  #pragma unroll
  for (int r = 0; r < 4; ++r) { Mr[r] = -1e30f; Lr[r] = 0.f; }
  const float CSC = 0.125f * 1.44269504f;  // SCALE * log2(e)
  for (int c0 = 0; c0 < SEQ; c0 += 64) {
    #pragma unroll
    for (int p = 0; p < 2; ++p) {
      int eidx = ((p*4 + wid)*64 + lane) * 8;
      int key = eidx >> 6, h = eidx & 63;
      gload_lds16(base + (size_t)(c0 + key)*QKV_N + 64 + h, Ks + eidx);
    }
    #pragma unroll
    for (int it = 0; it < 2; ++it) {
      int idx = (it*256 + tid) * 8;
      int key = idx >> 6, h0 = idx & 63;
      union { short8 v; bf16 h[8]; } u;
      u.v = *(const short8*)(base + (size_t)(c0 + key)*QKV_N + 128 + h0);
      #pragma unroll
      for (int j = 0; j < 8; ++j) VTs[(h0 + j)*64 + key] = u.h[j];
    }
    __syncthreads();
    f32x4 sc[4] = {};
    #pragma unroll
    for (int kk = 0; kk < 2; ++kk) {
      #pragma unroll
      for (int ni = 0; ni < 4; ++ni) {
        short8 kf = *(const short8*)(Ks + (ni*16 + fr)*64 + kk*32 + fg*8);
        sc[ni] = __builtin_amdgcn_mfma_f32_16x16x32_bf16(qf[kk], kf, sc[ni], 0, 0, 0);
      }
    }
    float Pf[4][4];
    #pragma unroll
    for (int r = 0; r < 4; ++r) {
      float mx = fmaxf(fmaxf(sc[0][r], sc[1][r]), fmaxf(sc[2][r], sc[3][r])) * CSC;
      #pragma unroll
      for (int m = 8; m >= 1; m >>= 1) mx = fmaxf(mx, __shfl_xor(mx, m));
      float Mn = fmaxf(Mr[r], mx);
      float so = exp2f(Mr[r] - Mn);
      Mr[r] = Mn;
      float ls = 0.f;
      #pragma unroll
      for (int ni = 0; ni < 4; ++ni) {
        float p = exp2f(sc[ni][r] * CSC - Mn);
        Pf[ni][r] = p; ls += p;
      }
      #pragma unroll
      for (int m = 8; m >= 1; m >>= 1) ls += __shfl_xor(ls, m);
      Lr[r] = Lr[r] * so + ls;
      #pragma unroll
      for (int hi = 0; hi < 4; ++hi) o[hi][r] *= so;
    }
    #pragma unroll
    for (int r = 0; r < 4; ++r) {
      #pragma unroll
      for (int ni = 0; ni < 4; ++ni)
        Ps[wid][(fg*4 + r)*64 + ni*16 + fr] = __float2bfloat16(Pf[ni][r]);
    }
    #pragma unroll
    for (int kk = 0; kk < 2; ++kk) {
      short8 pf = *(const short8*)(&Ps[wid][fr*64 + kk*32 + fg*8]);
      #pragma unroll
      for (int hi = 0; hi < 4; ++hi) {
        short8 vf = *(const short8*)(VTs + (hi*16 + fr)*64 + kk*32 + fg*8);
        o[hi] = __builtin_amdgcn_mfma_f32_16x16x32_bf16(pf, vf, o[hi], 0, 0, 0);
      }
    }
    __syncthreads();
  }
  const int rowb = b * SEQ + s0 + wid*16 + fg*4;
  #pragma unroll
  for (int r = 0; r < 4; ++r) {
    const float g = gates[(size_t)(rowb + r) * NUM_EXPERTS + e];
    const float inv = g / Lr[r];
    #pragma unroll
    for (int hi = 0; hi < 4; ++hi)
      combined[(size_t)(rowb + r) * D_MODEL + e*64 + hi*16 + fr] =
          __float2bfloat16(o[hi][r] * inv);
  }
}

extern "C" void kernel_launch(void* const* d_in, const int* in_sizes, int n_in,
                              void* d_out, int out_size, void* d_ws, size_t ws_size,
                              hipStream_t stream) {
  const float* x    = (const float*)d_in[0];
  const float* wqkv = (const float*)d_in[1];
  const float* bqkv = (const float*)d_in[2];
  const float* rw   = (const float*)d_in[3];
  const float* rb   = (const float*)d_in[4];
  const float* ow   = (const float*)d_in[5];
  const float* ob   = (const float*)d_in[6];
  char* ws = (char*)d_ws;
  bf16*  xb    = (bf16*)(ws);                    // 4096*1280*2      = 10485760
  bf16*  wqkvT = (bf16*)(ws + 10485760);         // 20*192*1280*2    =  9830400
  bf16*  owT   = (bf16*)(ws + 20316160);         // 1280*1280*2      =  3276800
  float* gates = (float*)(ws + 23592960);        // 4096*20*4        =   327680
  bf16*  qkv   = (bf16*)(ws + 23920640);         // 20*4096*192*2    = 31457280
  bf16*  comb  = (bf16*)(ws + 55377920);         // 4096*1280*2      = 10485760

  k_gates<<<4096, 256, 0, stream>>>(x, rw, rb, gates, xb);
  k_transpose<<<dim3(6, 40, 20), dim3(32, 8), 0, stream>>>(wqkv, wqkvT, D_MODEL, QKV_N);
  k_transpose<<<dim3(40, 40, 1), dim3(32, 8), 0, stream>>>(ow, owT, D_MODEL, D_MODEL);
  k_gemm<true><<<dim3(32, 3, 20), 256, 0, stream>>>(xb, wqkvT, bqkv, qkv,
                                                    BS_TOK, QKV_N, D_MODEL);
  k_attn<<<dim3(16, BATCH, NUM_EXPERTS), 256, 0, stream>>>(qkv, gates, comb);
  k_gemm<false><<<dim3(32, 20, 1), 256, 0, stream>>>(comb, owT, ob, d_out,
                                                     BS_TOK, D_MODEL, D_MODEL);
}

// Round 2
// 261.453 us; speedup vs baseline: 1.3962x; 1.3962x over previous
//
#include <hip/hip_runtime.h>
#include <hip/hip_bf16.h>

#define D_MODEL 1280
#define NUM_EXPERTS 20
#define HEAD_DIM 64
#define SEQ 1024
#define BATCH 4
#define BS_TOK 4096
#define QKV_N 192

typedef __attribute__((ext_vector_type(8))) short short8;
typedef __attribute__((ext_vector_type(4))) float f32x4;
typedef __hip_bfloat16 bf16;

static __device__ __forceinline__ void gload_lds16(const void* g, void* l) {
  __builtin_amdgcn_global_load_lds((const __attribute__((address_space(1))) void*)g,
                                   (__attribute__((address_space(3))) void*)l, 16, 0, 0);
}

// ---------------- router_w [D][E] f32 -> rwT [E][D] f32 ----------------
__global__ __launch_bounds__(256) void k_rwT(const float* __restrict__ in,
                                             float* __restrict__ out) {
  int i = blockIdx.x * 256 + threadIdx.x;
  if (i < D_MODEL * NUM_EXPERTS) {
    int d = i / NUM_EXPERTS, e = i % NUM_EXPERTS;
    out[e * D_MODEL + d] = in[i];
  }
}

// ---------------- router gates + x -> bf16 (4 rows/block, wave per row) ----
__global__ __launch_bounds__(256) void k_gates(const float* __restrict__ x,
    const float* __restrict__ rwT, const float* __restrict__ rb,
    float* __restrict__ gates, bf16* __restrict__ xb)
{
  __shared__ float xs[4][D_MODEL];
  __shared__ float logits[4][NUM_EXPERTS];
  const int r0 = blockIdx.x * 4;
  for (int i = threadIdx.x; i < 4 * (D_MODEL / 2); i += 256) {
    int r = i / (D_MODEL / 2), d2 = (i % (D_MODEL / 2)) * 2;
    float2 v = *(const float2*)(x + (size_t)(r0 + r) * D_MODEL + d2);
    xs[r][d2] = v.x; xs[r][d2 + 1] = v.y;
    __hip_bfloat162 h;
    h.x = __float2bfloat16(v.x); h.y = __float2bfloat16(v.y);
    *(__hip_bfloat162*)(xb + (size_t)(r0 + r) * D_MODEL + d2) = h;
  }
  __syncthreads();
  const int wid = threadIdx.x >> 6, lane = threadIdx.x & 63;
  // wave `wid` computes all expert logits for row r0+wid
  for (int e = 0; e < NUM_EXPERTS; ++e) {
    float s = 0.f;
    #pragma unroll
    for (int j = 0; j < D_MODEL / 64; ++j) {
      int d = lane + 64 * j;
      s += xs[wid][d] * rwT[e * D_MODEL + d];
    }
    #pragma unroll
    for (int m = 32; m >= 1; m >>= 1) s += __shfl_xor(s, m);
    if (lane == 0) logits[wid][e] = s + rb[e];
  }
  __syncthreads();
  if (lane < 32) {
    float v = (lane < NUM_EXPERTS) ? logits[wid][lane] : -1e30f;
    float mx = v;
    #pragma unroll
    for (int m = 16; m >= 1; m >>= 1) mx = fmaxf(mx, __shfl_xor(mx, m, 32));
    float p = (lane < NUM_EXPERTS) ? __expf(v - mx) : 0.f;
    float sum = p;
    #pragma unroll
    for (int m = 16; m >= 1; m >>= 1) sum += __shfl_xor(sum, m, 32);
    if (lane < NUM_EXPERTS)
      gates[(size_t)(r0 + wid) * NUM_EXPERTS + lane] = p / sum;
  }
}

// ---------------- f32 [batch][R][C] -> bf16 [batch][C][R] ----------------
__global__ __launch_bounds__(256) void k_transpose(const float* __restrict__ in,
    bf16* __restrict__ out, int R, int C)
{
  __shared__ float tile[32][33];
  const size_t bo = (size_t)blockIdx.z * R * C;
  const int c0 = blockIdx.x * 32, r0 = blockIdx.y * 32;
  const int tx = threadIdx.x, ty = threadIdx.y;  // block (32,8)
  #pragma unroll
  for (int i = 0; i < 4; ++i)
    tile[ty + 8*i][tx] = in[bo + (size_t)(r0 + ty + 8*i) * C + (c0 + tx)];
  __syncthreads();
  #pragma unroll
  for (int i = 0; i < 4; ++i)
    out[bo + (size_t)(c0 + ty + 8*i) * R + (r0 + tx)] =
        __float2bfloat16(tile[tx][ty + 8*i]);
}

// ---------------- bf16 MFMA GEMM: C[e] = A @ B[e]^T + bias ----------------
// A [M,K] row-major bf16; BT [batch][N,K] row-major bf16; bias [batch][N] f32
// grid (M/128, N/64, batch), 256 threads (4 waves, 2x2 wave grid, 64x32 each)
template<bool OUT_BF16>
__global__ __launch_bounds__(256) void k_gemm(
    const bf16* __restrict__ A, const bf16* __restrict__ BT,
    const float* __restrict__ bias, void* __restrict__ C,
    int M, int N, int K)
{
  __shared__ __align__(16) bf16 As[128 * 64];
  __shared__ __align__(16) bf16 Bs[64 * 64];
  const int e = blockIdx.z;
  const int m0 = blockIdx.x * 128, n0 = blockIdx.y * 64;
  const int tid = threadIdx.x, wid = tid >> 6, lane = tid & 63;
  const int wr = wid >> 1, wc = wid & 1;
  const int fr = lane & 15, fg = lane >> 4;
  const bf16* Be = BT + (size_t)e * N * K;
  f32x4 acc[4][2] = {};
  for (int k0 = 0; k0 < K; k0 += 64) {
    #pragma unroll
    for (int p = 0; p < 4; ++p) {
      int eidx = ((p*4 + wid)*64 + lane) * 8;
      int row = eidx >> 6, col = eidx & 63;
      gload_lds16(A + (size_t)(m0 + row)*K + k0 + col, As + eidx);
    }
    #pragma unroll
    for (int p = 0; p < 2; ++p) {
      int eidx = ((p*4 + wid)*64 + lane) * 8;
      int row = eidx >> 6, col = eidx & 63;
      gload_lds16(Be + (size_t)(n0 + row)*K + k0 + col, Bs + eidx);
    }
    __syncthreads();
    short8 af[2][4], bfr[2][2];
    #pragma unroll
    for (int kk = 0; kk < 2; ++kk) {
      #pragma unroll
      for (int mi = 0; mi < 4; ++mi)
        af[kk][mi] = *(const short8*)(As + (wr*64 + mi*16 + fr)*64 + kk*32 + fg*8);
      #pragma unroll
      for (int ni = 0; ni < 2; ++ni)
        bfr[kk][ni] = *(const short8*)(Bs + (wc*32 + ni*16 + fr)*64 + kk*32 + fg*8);
    }
    #pragma unroll
    for (int kk = 0; kk < 2; ++kk) {
      #pragma unroll
      for (int mi = 0; mi < 4; ++mi) {
        #pragma unroll
        for (int ni = 0; ni < 2; ++ni)
          acc[mi][ni] = __builtin_amdgcn_mfma_f32_16x16x32_bf16(
              af[kk][mi], bfr[kk][ni], acc[mi][ni], 0, 0, 0);
      }
    }
    __syncthreads();
  }
  #pragma unroll
  for (int mi = 0; mi < 4; ++mi) {
    const int gr = m0 + wr*64 + mi*16 + fg*4;
    #pragma unroll
    for (int ni = 0; ni < 2; ++ni) {
      const int gc = n0 + wc*32 + ni*16 + fr;
      const float bv = bias[(size_t)e * N + gc];
      #pragma unroll
      for (int r = 0; r < 4; ++r) {
        float v = acc[mi][ni][r] + bv;
        size_t off = ((size_t)e * M + gr + r) * N + gc;
        if constexpr (OUT_BF16) ((bf16*)C)[off] = __float2bfloat16(v);
        else                    ((float*)C)[off] = v;
      }
    }
  }
}

// ---------------- flash attention per (qtile, b, e) ----------------
// qkv [E][BS_TOK][192] bf16 (q|k|v), gates [BS_TOK][E] f32
// out: combined [BS_TOK][1280] bf16 (slice e*64)
__global__ __launch_bounds__(256) void k_attn(
    const bf16* __restrict__ qkv, const float* __restrict__ gates,
    bf16* __restrict__ combined)
{
  __shared__ __align__(16) bf16 Ks[64 * 64];   // [key][h]
  __shared__ __align__(16) bf16 VTs[64 * 64];  // [h][key]
  __shared__ __align__(16) bf16 Ps[4][16 * 64];// per-wave P [q16][key64]
  const int e = blockIdx.z, b = blockIdx.y, s0 = blockIdx.x * 64;
  const int tid = threadIdx.x, wid = tid >> 6, lane = tid & 63;
  const int fr = lane & 15, fg = lane >> 4;
  const bf16* base = qkv + ((size_t)e * BS_TOK + b * SEQ) * QKV_N;
  short8 qf[2];
  #pragma unroll
  for (int kk = 0; kk < 2; ++kk)
    qf[kk] = *(const short8*)(base + (size_t)(s0 + wid*16 + fr) * QKV_N + kk*32 + fg*8);
  f32x4 o[4] = {};
  float Mr[4], Lr[4];
  #pragma unroll
  for (int r = 0; r < 4; ++r) { Mr[r] = -1e30f; Lr[r] = 0.f; }
  const float CSC = 0.125f * 1.44269504f;  // SCALE * log2(e)
  for (int c0 = 0; c0 < SEQ; c0 += 64) {
    #pragma unroll
    for (int p = 0; p < 2; ++p) {
      int eidx = ((p*4 + wid)*64 + lane) * 8;
      int key = eidx >> 6, h = eidx & 63;
      gload_lds16(base + (size_t)(c0 + key)*QKV_N + 64 + h, Ks + eidx);
    }
    #pragma unroll
    for (int it = 0; it < 2; ++it) {
      int idx = (it*256 + tid) * 8;
      int key = idx >> 6, h0 = idx & 63;
      union { short8 v; bf16 h[8]; } u;
      u.v = *(const short8*)(base + (size_t)(c0 + key)*QKV_N + 128 + h0);
      #pragma unroll
      for (int j = 0; j < 8; ++j) VTs[(h0 + j)*64 + key] = u.h[j];
    }
    __syncthreads();
    f32x4 sc[4] = {};
    #pragma unroll
    for (int kk = 0; kk < 2; ++kk) {
      #pragma unroll
      for (int ni = 0; ni < 4; ++ni) {
        short8 kf = *(const short8*)(Ks + (ni*16 + fr)*64 + kk*32 + fg*8);
        sc[ni] = __builtin_amdgcn_mfma_f32_16x16x32_bf16(qf[kk], kf, sc[ni], 0, 0, 0);
      }
    }
    float Pf[4][4];
    #pragma unroll
    for (int r = 0; r < 4; ++r) {
      float mx = fmaxf(fmaxf(sc[0][r], sc[1][r]), fmaxf(sc[2][r], sc[3][r])) * CSC;
      #pragma unroll
      for (int m = 8; m >= 1; m >>= 1) mx = fmaxf(mx, __shfl_xor(mx, m));
      float Mn = fmaxf(Mr[r], mx);
      float so = exp2f(Mr[r] - Mn);
      Mr[r] = Mn;
      float ls = 0.f;
      #pragma unroll
      for (int ni = 0; ni < 4; ++ni) {
        float p = exp2f(sc[ni][r] * CSC - Mn);
        Pf[ni][r] = p; ls += p;
      }
      #pragma unroll
      for (int m = 8; m >= 1; m >>= 1) ls += __shfl_xor(ls, m);
      Lr[r] = Lr[r] * so + ls;
      #pragma unroll
      for (int hi = 0; hi < 4; ++hi) o[hi][r] *= so;
    }
    #pragma unroll
    for (int r = 0; r < 4; ++r) {
      #pragma unroll
      for (int ni = 0; ni < 4; ++ni)
        Ps[wid][(fg*4 + r)*64 + ni*16 + fr] = __float2bfloat16(Pf[ni][r]);
    }
    #pragma unroll
    for (int kk = 0; kk < 2; ++kk) {
      short8 pf = *(const short8*)(&Ps[wid][fr*64 + kk*32 + fg*8]);
      #pragma unroll
      for (int hi = 0; hi < 4; ++hi) {
        short8 vf = *(const short8*)(VTs + (hi*16 + fr)*64 + kk*32 + fg*8);
        o[hi] = __builtin_amdgcn_mfma_f32_16x16x32_bf16(pf, vf, o[hi], 0, 0, 0);
      }
    }
    __syncthreads();
  }
  const int rowb = b * SEQ + s0 + wid*16 + fg*4;
  #pragma unroll
  for (int r = 0; r < 4; ++r) {
    const float g = gates[(size_t)(rowb + r) * NUM_EXPERTS + e];
    const float inv = g / Lr[r];
    #pragma unroll
    for (int hi = 0; hi < 4; ++hi)
      combined[(size_t)(rowb + r) * D_MODEL + e*64 + hi*16 + fr] =
          __float2bfloat16(o[hi][r] * inv);
  }
}

extern "C" void kernel_launch(void* const* d_in, const int* in_sizes, int n_in,
                              void* d_out, int out_size, void* d_ws, size_t ws_size,
                              hipStream_t stream) {
  const float* x    = (const float*)d_in[0];
  const float* wqkv = (const float*)d_in[1];
  const float* bqkv = (const float*)d_in[2];
  const float* rw   = (const float*)d_in[3];
  const float* rb   = (const float*)d_in[4];
  const float* ow   = (const float*)d_in[5];
  const float* ob   = (const float*)d_in[6];
  char* ws = (char*)d_ws;
  bf16*  xb    = (bf16*)(ws);                    // 4096*1280*2      = 10485760
  bf16*  wqkvT = (bf16*)(ws + 10485760);         // 20*192*1280*2    =  9830400
  bf16*  owT   = (bf16*)(ws + 20316160);         // 1280*1280*2      =  3276800
  float* gates = (float*)(ws + 23592960);        // 4096*20*4        =   327680
  bf16*  qkv   = (bf16*)(ws + 23920640);         // 20*4096*192*2    = 31457280
  bf16*  comb  = (bf16*)(ws + 55377920);         // 4096*1280*2      = 10485760
  // rwT aliases comb: consumed by k_gates before k_attn overwrites comb.
  float* rwT   = (float*)comb;                   // 20*1280*4        =   102400

  k_rwT<<<(D_MODEL * NUM_EXPERTS + 255) / 256, 256, 0, stream>>>(rw, rwT);
  k_gates<<<1024, 256, 0, stream>>>(x, rwT, rb, gates, xb);
  k_transpose<<<dim3(6, 40, 20), dim3(32, 8), 0, stream>>>(wqkv, wqkvT, D_MODEL, QKV_N);
  k_transpose<<<dim3(40, 40, 1), dim3(32, 8), 0, stream>>>(ow, owT, D_MODEL, D_MODEL);
  k_gemm<true><<<dim3(32, 3, 20), 256, 0, stream>>>(xb, wqkvT, bqkv, qkv,
                                                    BS_TOK, QKV_N, D_MODEL);
  k_attn<<<dim3(16, BATCH, NUM_EXPERTS), 256, 0, stream>>>(qkv, gates, comb);
  k_gemm<false><<<dim3(32, 20, 1), 256, 0, stream>>>(comb, owT, ob, d_out,
                                                     BS_TOK, D_MODEL, D_MODEL);
}

// Round 3
// 233.670 us; speedup vs baseline: 1.5622x; 1.1189x over previous
//
#include <hip/hip_runtime.h>
#include <hip/hip_bf16.h>

#define D_MODEL 1280
#define NUM_EXPERTS 20
#define HEAD_DIM 64
#define SEQ 1024
#define BATCH 4
#define BS_TOK 4096
#define QKV_N 192

typedef __attribute__((ext_vector_type(8))) short short8;
typedef __attribute__((ext_vector_type(4))) float f32x4;
typedef __hip_bfloat16 bf16;

static __device__ __forceinline__ void gload_lds16(const void* g, void* l) {
  __builtin_amdgcn_global_load_lds((const __attribute__((address_space(1))) void*)g,
                                   (__attribute__((address_space(3))) void*)l, 16, 0, 0);
}

// ---------------- router_w [D][E] f32 -> rwT [E][D] f32 ----------------
__global__ __launch_bounds__(256) void k_rwT(const float* __restrict__ in,
                                             float* __restrict__ out) {
  int i = blockIdx.x * 256 + threadIdx.x;
  if (i < D_MODEL * NUM_EXPERTS) {
    int d = i / NUM_EXPERTS, e = i % NUM_EXPERTS;
    out[e * D_MODEL + d] = in[i];
  }
}

// ---------------- router gates + x -> bf16 (4 rows/block, wave per row) ----
__global__ __launch_bounds__(256) void k_gates(const float* __restrict__ x,
    const float* __restrict__ rwT, const float* __restrict__ rb,
    float* __restrict__ gates, bf16* __restrict__ xb)
{
  __shared__ float xs[4][D_MODEL];
  __shared__ float logits[4][NUM_EXPERTS];
  const int r0 = blockIdx.x * 4;
  for (int i = threadIdx.x; i < 4 * (D_MODEL / 2); i += 256) {
    int r = i / (D_MODEL / 2), d2 = (i % (D_MODEL / 2)) * 2;
    float2 v = *(const float2*)(x + (size_t)(r0 + r) * D_MODEL + d2);
    xs[r][d2] = v.x; xs[r][d2 + 1] = v.y;
    __hip_bfloat162 h;
    h.x = __float2bfloat16(v.x); h.y = __float2bfloat16(v.y);
    *(__hip_bfloat162*)(xb + (size_t)(r0 + r) * D_MODEL + d2) = h;
  }
  __syncthreads();
  const int wid = threadIdx.x >> 6, lane = threadIdx.x & 63;
  for (int e = 0; e < NUM_EXPERTS; ++e) {
    float s = 0.f;
    #pragma unroll
    for (int j = 0; j < D_MODEL / 64; ++j) {
      int d = lane + 64 * j;
      s += xs[wid][d] * rwT[e * D_MODEL + d];
    }
    #pragma unroll
    for (int m = 32; m >= 1; m >>= 1) s += __shfl_xor(s, m);
    if (lane == 0) logits[wid][e] = s + rb[e];
  }
  __syncthreads();
  if (lane < 32) {
    float v = (lane < NUM_EXPERTS) ? logits[wid][lane] : -1e30f;
    float mx = v;
    #pragma unroll
    for (int m = 16; m >= 1; m >>= 1) mx = fmaxf(mx, __shfl_xor(mx, m, 32));
    float p = (lane < NUM_EXPERTS) ? __expf(v - mx) : 0.f;
    float sum = p;
    #pragma unroll
    for (int m = 16; m >= 1; m >>= 1) sum += __shfl_xor(sum, m, 32);
    if (lane < NUM_EXPERTS)
      gates[(size_t)(r0 + wid) * NUM_EXPERTS + lane] = p / sum;
  }
}

// ---------------- f32 [batch][R][C] -> bf16 [batch][C][R] ----------------
__global__ __launch_bounds__(256) void k_transpose(const float* __restrict__ in,
    bf16* __restrict__ out, int R, int C)
{
  __shared__ float tile[32][33];
  const size_t bo = (size_t)blockIdx.z * R * C;
  const int c0 = blockIdx.x * 32, r0 = blockIdx.y * 32;
  const int tx = threadIdx.x, ty = threadIdx.y;  // block (32,8)
  #pragma unroll
  for (int i = 0; i < 4; ++i)
    tile[ty + 8*i][tx] = in[bo + (size_t)(r0 + ty + 8*i) * C + (c0 + tx)];
  __syncthreads();
  #pragma unroll
  for (int i = 0; i < 4; ++i)
    out[bo + (size_t)(c0 + ty + 8*i) * R + (r0 + tx)] =
        __float2bfloat16(tile[tx][ty + 8*i]);
}

// ---------------- bf16 MFMA GEMM: C[e] = A @ B[e]^T + bias ----------------
template<bool OUT_BF16>
__global__ __launch_bounds__(256) void k_gemm(
    const bf16* __restrict__ A, const bf16* __restrict__ BT,
    const float* __restrict__ bias, void* __restrict__ C,
    int M, int N, int K)
{
  __shared__ __align__(16) bf16 As[128 * 64];
  __shared__ __align__(16) bf16 Bs[64 * 64];
  const int e = blockIdx.z;
  const int m0 = blockIdx.x * 128, n0 = blockIdx.y * 64;
  const int tid = threadIdx.x, wid = tid >> 6, lane = tid & 63;
  const int wr = wid >> 1, wc = wid & 1;
  const int fr = lane & 15, fg = lane >> 4;
  const bf16* Be = BT + (size_t)e * N * K;
  f32x4 acc[4][2] = {};
  for (int k0 = 0; k0 < K; k0 += 64) {
    #pragma unroll
    for (int p = 0; p < 4; ++p) {
      int eidx = ((p*4 + wid)*64 + lane) * 8;
      int row = eidx >> 6, col = eidx & 63;
      gload_lds16(A + (size_t)(m0 + row)*K + k0 + col, As + eidx);
    }
    #pragma unroll
    for (int p = 0; p < 2; ++p) {
      int eidx = ((p*4 + wid)*64 + lane) * 8;
      int row = eidx >> 6, col = eidx & 63;
      gload_lds16(Be + (size_t)(n0 + row)*K + k0 + col, Bs + eidx);
    }
    __syncthreads();
    short8 af[2][4], bfr[2][2];
    #pragma unroll
    for (int kk = 0; kk < 2; ++kk) {
      #pragma unroll
      for (int mi = 0; mi < 4; ++mi)
        af[kk][mi] = *(const short8*)(As + (wr*64 + mi*16 + fr)*64 + kk*32 + fg*8);
      #pragma unroll
      for (int ni = 0; ni < 2; ++ni)
        bfr[kk][ni] = *(const short8*)(Bs + (wc*32 + ni*16 + fr)*64 + kk*32 + fg*8);
    }
    #pragma unroll
    for (int kk = 0; kk < 2; ++kk) {
      #pragma unroll
      for (int mi = 0; mi < 4; ++mi) {
        #pragma unroll
        for (int ni = 0; ni < 2; ++ni)
          acc[mi][ni] = __builtin_amdgcn_mfma_f32_16x16x32_bf16(
              af[kk][mi], bfr[kk][ni], acc[mi][ni], 0, 0, 0);
      }
    }
    __syncthreads();
  }
  #pragma unroll
  for (int mi = 0; mi < 4; ++mi) {
    const int gr = m0 + wr*64 + mi*16 + fg*4;
    #pragma unroll
    for (int ni = 0; ni < 2; ++ni) {
      const int gc = n0 + wc*32 + ni*16 + fr;
      const float bv = bias[(size_t)e * N + gc];
      #pragma unroll
      for (int r = 0; r < 4; ++r) {
        float v = acc[mi][ni][r] + bv;
        size_t off = ((size_t)e * M + gr + r) * N + gc;
        if constexpr (OUT_BF16) ((bf16*)C)[off] = __float2bfloat16(v);
        else                    ((float*)C)[off] = v;
      }
    }
  }
}

// ---------------- flash attention, bank-conflict-free LDS ----------------
// qkv [E][BS_TOK][192] bf16 (q|k|v), gates [BS_TOK][E] f32
// flat grid 1280, XCD-aware decode so all q-tiles of one (b,e) share an XCD.
// Ks: [key][h-chunk swizzled]: slot c of row R holds global chunk c^(R>>3&7)
// VTs: [h][key-chunk swizzled by (h>>3)&7]
// Ps: row stride 72 bf16 (pad 8) to spread scalar writes
#define PS_LD 72
__global__ __launch_bounds__(256) void k_attn(
    const bf16* __restrict__ qkv, const float* __restrict__ gates,
    bf16* __restrict__ combined)
{
  __shared__ __align__(16) bf16 Ks[64 * 64];
  __shared__ __align__(16) bf16 VTs[64 * 64];
  __shared__ __align__(16) bf16 Ps[4][16 * PS_LD];
  const int id = blockIdx.x;
  const int x = id & 7, kgrp = id >> 3;
  const int qt = kgrp / 10, bel = kgrp - qt * 10;
  const int be = x * 10 + bel;
  const int e = be >> 2, b = be & 3;
  const int s0 = qt * 64;
  const int tid = threadIdx.x, wid = tid >> 6, lane = tid & 63;
  const int fr = lane & 15, fg = lane >> 4;
  const bf16* base = qkv + ((size_t)e * BS_TOK + b * SEQ) * QKV_N;
  short8 qf[2];
  #pragma unroll
  for (int kk = 0; kk < 2; ++kk)
    qf[kk] = *(const short8*)(base + (size_t)(s0 + wid*16 + fr) * QKV_N + kk*32 + fg*8);
  f32x4 o[4] = {};
  float Mr[4], Lr[4];
  #pragma unroll
  for (int r = 0; r < 4; ++r) { Mr[r] = -1e30f; Lr[r] = 0.f; }
  const float CSC = 0.125f * 1.44269504f;  // SCALE * log2(e)
  for (int c0 = 0; c0 < SEQ; c0 += 64) {
    // --- stage K with inverse-swizzled global source (linear LDS dest) ---
    #pragma unroll
    for (int p = 0; p < 2; ++p) {
      int s = (p*4 + wid) & 7;
      int row = (p*4 + wid)*8 + (lane >> 3);
      int cg = (lane & 7) ^ s;
      gload_lds16(base + (size_t)(c0 + row)*QKV_N + 64 + cg*8,
                  Ks + ((p*4 + wid)*64 + lane)*8);
    }
    // --- stage V transposed, key-chunk swizzled by (h>>3)&7 ---
    #pragma unroll
    for (int it = 0; it < 2; ++it) {
      int idx = (it*256 + tid) * 8;
      int key = idx >> 6, h0 = idx & 63;
      int p8 = (tid & 7) << 3;  // (h>>3)<<3 for this thread's h's
      union { short8 v; bf16 h[8]; } u;
      u.v = *(const short8*)(base + (size_t)(c0 + key)*QKV_N + 128 + h0);
      #pragma unroll
      for (int j = 0; j < 8; ++j)
        VTs[(h0 + j)*64 + (key ^ p8)] = u.h[j];
    }
    __syncthreads();
    // --- QK^T ---
    f32x4 sc[4] = {};
    #pragma unroll
    for (int kk = 0; kk < 2; ++kk) {
      #pragma unroll
      for (int ni = 0; ni < 4; ++ni) {
        int qR = (ni*2 + (fr >> 3)) & 7;
        short8 kf = *(const short8*)(Ks + (ni*16 + fr)*64 + (((kk*4 + fg) ^ qR) << 3));
        sc[ni] = __builtin_amdgcn_mfma_f32_16x16x32_bf16(qf[kk], kf, sc[ni], 0, 0, 0);
      }
    }
    // --- online softmax ---
    float Pf[4][4];
    #pragma unroll
    for (int r = 0; r < 4; ++r) {
      float mx = fmaxf(fmaxf(sc[0][r], sc[1][r]), fmaxf(sc[2][r], sc[3][r])) * CSC;
      #pragma unroll
      for (int m = 8; m >= 1; m >>= 1) mx = fmaxf(mx, __shfl_xor(mx, m));
      float Mn = fmaxf(Mr[r], mx);
      float so = exp2f(Mr[r] - Mn);
      Mr[r] = Mn;
      float ls = 0.f;
      #pragma unroll
      for (int ni = 0; ni < 4; ++ni) {
        float p = exp2f(sc[ni][r] * CSC - Mn);
        Pf[ni][r] = p; ls += p;
      }
      #pragma unroll
      for (int m = 8; m >= 1; m >>= 1) ls += __shfl_xor(ls, m);
      Lr[r] = Lr[r] * so + ls;
      #pragma unroll
      for (int hi = 0; hi < 4; ++hi) o[hi][r] *= so;
    }
    // --- P via padded LDS ---
    #pragma unroll
    for (int r = 0; r < 4; ++r) {
      #pragma unroll
      for (int ni = 0; ni < 4; ++ni)
        Ps[wid][(fg*4 + r)*PS_LD + ni*16 + fr] = __float2bfloat16(Pf[ni][r]);
    }
    // --- PV ---
    #pragma unroll
    for (int kk = 0; kk < 2; ++kk) {
      short8 pf = *(const short8*)(&Ps[wid][fr*PS_LD + kk*32 + fg*8]);
      #pragma unroll
      for (int hi = 0; hi < 4; ++hi) {
        int qh = (hi*2 + (fr >> 3)) & 7;
        short8 vf = *(const short8*)(VTs + (hi*16 + fr)*64 + (((kk*4 + fg) ^ qh) << 3));
        o[hi] = __builtin_amdgcn_mfma_f32_16x16x32_bf16(pf, vf, o[hi], 0, 0, 0);
      }
    }
    __syncthreads();
  }
  const int rowb = b * SEQ + s0 + wid*16 + fg*4;
  #pragma unroll
  for (int r = 0; r < 4; ++r) {
    const float g = gates[(size_t)(rowb + r) * NUM_EXPERTS + e];
    const float inv = g / Lr[r];
    #pragma unroll
    for (int hi = 0; hi < 4; ++hi)
      combined[(size_t)(rowb + r) * D_MODEL + e*64 + hi*16 + fr] =
          __float2bfloat16(o[hi][r] * inv);
  }
}

extern "C" void kernel_launch(void* const* d_in, const int* in_sizes, int n_in,
                              void* d_out, int out_size, void* d_ws, size_t ws_size,
                              hipStream_t stream) {
  const float* x    = (const float*)d_in[0];
  const float* wqkv = (const float*)d_in[1];
  const float* bqkv = (const float*)d_in[2];
  const float* rw   = (const float*)d_in[3];
  const float* rb   = (const float*)d_in[4];
  const float* ow   = (const float*)d_in[5];
  const float* ob   = (const float*)d_in[6];
  char* ws = (char*)d_ws;
  bf16*  xb    = (bf16*)(ws);                    // 4096*1280*2      = 10485760
  bf16*  wqkvT = (bf16*)(ws + 10485760);         // 20*192*1280*2    =  9830400
  bf16*  owT   = (bf16*)(ws + 20316160);         // 1280*1280*2      =  3276800
  float* gates = (float*)(ws + 23592960);        // 4096*20*4        =   327680
  bf16*  qkv   = (bf16*)(ws + 23920640);         // 20*4096*192*2    = 31457280
  bf16*  comb  = (bf16*)(ws + 55377920);         // 4096*1280*2      = 10485760
  float* rwT   = (float*)comb;                   // aliased, consumed pre-attn

  k_rwT<<<(D_MODEL * NUM_EXPERTS + 255) / 256, 256, 0, stream>>>(rw, rwT);
  k_gates<<<1024, 256, 0, stream>>>(x, rwT, rb, gates, xb);
  k_transpose<<<dim3(6, 40, 20), dim3(32, 8), 0, stream>>>(wqkv, wqkvT, D_MODEL, QKV_N);
  k_transpose<<<dim3(40, 40, 1), dim3(32, 8), 0, stream>>>(ow, owT, D_MODEL, D_MODEL);
  k_gemm<true><<<dim3(32, 3, 20), 256, 0, stream>>>(xb, wqkvT, bqkv, qkv,
                                                    BS_TOK, QKV_N, D_MODEL);
  k_attn<<<1280, 256, 0, stream>>>(qkv, gates, comb);
  k_gemm<false><<<dim3(32, 20, 1), 256, 0, stream>>>(comb, owT, ob, d_out,
                                                     BS_TOK, D_MODEL, D_MODEL);
}

// Round 4
// 228.595 us; speedup vs baseline: 1.5969x; 1.0222x over previous
//
#include <hip/hip_runtime.h>
#include <hip/hip_bf16.h>

#define D_MODEL 1280
#define NUM_EXPERTS 20
#define HEAD_DIM 64
#define SEQ 1024
#define BATCH 4
#define BS_TOK 4096
#define QKV_N 192

typedef __attribute__((ext_vector_type(8))) short short8;
typedef __attribute__((ext_vector_type(4))) float f32x4;
typedef __hip_bfloat16 bf16;

static __device__ __forceinline__ void gload_lds16(const void* g, void* l) {
  __builtin_amdgcn_global_load_lds((const __attribute__((address_space(1))) void*)g,
                                   (__attribute__((address_space(3))) void*)l, 16, 0, 0);
}

// ---------------- router_w [D][E] f32 -> rwT [E][D] f32 ----------------
__global__ __launch_bounds__(256) void k_rwT(const float* __restrict__ in,
                                             float* __restrict__ out) {
  int i = blockIdx.x * 256 + threadIdx.x;
  if (i < D_MODEL * NUM_EXPERTS) {
    int d = i / NUM_EXPERTS, e = i % NUM_EXPERTS;
    out[e * D_MODEL + d] = in[i];
  }
}

// ---------------- router gates + x -> bf16 (4 rows/block, wave per row) ----
__global__ __launch_bounds__(256) void k_gates(const float* __restrict__ x,
    const float* __restrict__ rwT, const float* __restrict__ rb,
    float* __restrict__ gates, bf16* __restrict__ xb)
{
  __shared__ float xs[4][D_MODEL];
  __shared__ float logits[4][NUM_EXPERTS];
  const int r0 = blockIdx.x * 4;
  for (int i = threadIdx.x; i < 4 * (D_MODEL / 2); i += 256) {
    int r = i / (D_MODEL / 2), d2 = (i % (D_MODEL / 2)) * 2;
    float2 v = *(const float2*)(x + (size_t)(r0 + r) * D_MODEL + d2);
    xs[r][d2] = v.x; xs[r][d2 + 1] = v.y;
    __hip_bfloat162 h;
    h.x = __float2bfloat16(v.x); h.y = __float2bfloat16(v.y);
    *(__hip_bfloat162*)(xb + (size_t)(r0 + r) * D_MODEL + d2) = h;
  }
  __syncthreads();
  const int wid = threadIdx.x >> 6, lane = threadIdx.x & 63;
  for (int e = 0; e < NUM_EXPERTS; ++e) {
    float s = 0.f;
    #pragma unroll
    for (int j = 0; j < D_MODEL / 64; ++j) {
      int d = lane + 64 * j;
      s += xs[wid][d] * rwT[e * D_MODEL + d];
    }
    #pragma unroll
    for (int m = 32; m >= 1; m >>= 1) s += __shfl_xor(s, m);
    if (lane == 0) logits[wid][e] = s + rb[e];
  }
  __syncthreads();
  if (lane < 32) {
    float v = (lane < NUM_EXPERTS) ? logits[wid][lane] : -1e30f;
    float mx = v;
    #pragma unroll
    for (int m = 16; m >= 1; m >>= 1) mx = fmaxf(mx, __shfl_xor(mx, m, 32));
    float p = (lane < NUM_EXPERTS) ? __expf(v - mx) : 0.f;
    float sum = p;
    #pragma unroll
    for (int m = 16; m >= 1; m >>= 1) sum += __shfl_xor(sum, m, 32);
    if (lane < NUM_EXPERTS)
      gates[(size_t)(r0 + wid) * NUM_EXPERTS + lane] = p / sum;
  }
}

// ---------------- f32 [batch][R][C] -> bf16 [batch][C][R] ----------------
__global__ __launch_bounds__(256) void k_transpose(const float* __restrict__ in,
    bf16* __restrict__ out, int R, int C)
{
  __shared__ float tile[32][33];
  const size_t bo = (size_t)blockIdx.z * R * C;
  const int c0 = blockIdx.x * 32, r0 = blockIdx.y * 32;
  const int tx = threadIdx.x, ty = threadIdx.y;  // block (32,8)
  #pragma unroll
  for (int i = 0; i < 4; ++i)
    tile[ty + 8*i][tx] = in[bo + (size_t)(r0 + ty + 8*i) * C + (c0 + tx)];
  __syncthreads();
  #pragma unroll
  for (int i = 0; i < 4; ++i)
    out[bo + (size_t)(c0 + ty + 8*i) * R + (r0 + tx)] =
        __float2bfloat16(tile[tx][ty + 8*i]);
}

// ---------------- bf16 MFMA GEMM: C[e] = A @ B[e]^T + bias ----------------
template<bool OUT_BF16>
__global__ __launch_bounds__(256) void k_gemm(
    const bf16* __restrict__ A, const bf16* __restrict__ BT,
    const float* __restrict__ bias, void* __restrict__ C,
    int M, int N, int K)
{
  __shared__ __align__(16) bf16 As[128 * 64];
  __shared__ __align__(16) bf16 Bs[64 * 64];
  const int e = blockIdx.z;
  const int m0 = blockIdx.x * 128, n0 = blockIdx.y * 64;
  const int tid = threadIdx.x, wid = tid >> 6, lane = tid & 63;
  const int wr = wid >> 1, wc = wid & 1;
  const int fr = lane & 15, fg = lane >> 4;
  const bf16* Be = BT + (size_t)e * N * K;
  f32x4 acc[4][2] = {};
  for (int k0 = 0; k0 < K; k0 += 64) {
    #pragma unroll
    for (int p = 0; p < 4; ++p) {
      int eidx = ((p*4 + wid)*64 + lane) * 8;
      int row = eidx >> 6, col = eidx & 63;
      gload_lds16(A + (size_t)(m0 + row)*K + k0 + col, As + eidx);
    }
    #pragma unroll
    for (int p = 0; p < 2; ++p) {
      int eidx = ((p*4 + wid)*64 + lane) * 8;
      int row = eidx >> 6, col = eidx & 63;
      gload_lds16(Be + (size_t)(n0 + row)*K + k0 + col, Bs + eidx);
    }
    __syncthreads();
    short8 af[2][4], bfr[2][2];
    #pragma unroll
    for (int kk = 0; kk < 2; ++kk) {
      #pragma unroll
      for (int mi = 0; mi < 4; ++mi)
        af[kk][mi] = *(const short8*)(As + (wr*64 + mi*16 + fr)*64 + kk*32 + fg*8);
      #pragma unroll
      for (int ni = 0; ni < 2; ++ni)
        bfr[kk][ni] = *(const short8*)(Bs + (wc*32 + ni*16 + fr)*64 + kk*32 + fg*8);
    }
    #pragma unroll
    for (int kk = 0; kk < 2; ++kk) {
      #pragma unroll
      for (int mi = 0; mi < 4; ++mi) {
        #pragma unroll
        for (int ni = 0; ni < 2; ++ni)
          acc[mi][ni] = __builtin_amdgcn_mfma_f32_16x16x32_bf16(
              af[kk][mi], bfr[kk][ni], acc[mi][ni], 0, 0, 0);
      }
    }
    __syncthreads();
  }
  #pragma unroll
  for (int mi = 0; mi < 4; ++mi) {
    const int gr = m0 + wr*64 + mi*16 + fg*4;
    #pragma unroll
    for (int ni = 0; ni < 2; ++ni) {
      const int gc = n0 + wc*32 + ni*16 + fr;
      const float bv = bias[(size_t)e * N + gc];
      #pragma unroll
      for (int r = 0; r < 4; ++r) {
        float v = acc[mi][ni][r] + bv;
        size_t off = ((size_t)e * M + gr + r) * N + gc;
        if constexpr (OUT_BF16) ((bf16*)C)[off] = __float2bfloat16(v);
        else                    ((float*)C)[off] = v;
      }
    }
  }
}

// ---------------- flash attention, conflict-free LDS (S = row>>3 ^ row&7) --
// Ks/VTs: [row][8 chunks of 8 bf16]; stored chunk sc holds logical chunk
// sc ^ S(row), S(row) = ((row>>3) ^ (row&7)) & 7.
// Ps: row stride 72 bf16 (pad 8).
#define PS_LD 72
__global__ __launch_bounds__(256) void k_attn(
    const bf16* __restrict__ qkv, const float* __restrict__ gates,
    bf16* __restrict__ combined)
{
  __shared__ __align__(16) bf16 Ks[64 * 64];
  __shared__ __align__(16) bf16 VTs[64 * 64];
  __shared__ __align__(16) bf16 Ps[4][16 * PS_LD];
  const int id = blockIdx.x;
  const int xcd = id & 7, kgrp = id >> 3;
  const int qt = kgrp / 10, bel = kgrp - qt * 10;
  const int be = xcd * 10 + bel;
  const int e = be >> 2, b = be & 3;
  const int s0 = qt * 64;
  const int tid = threadIdx.x, wid = tid >> 6, lane = tid & 63;
  const int fr = lane & 15, fg = lane >> 4;
  const bf16* base = qkv + ((size_t)e * BS_TOK + b * SEQ) * QKV_N;
  short8 qf[2];
  #pragma unroll
  for (int kk = 0; kk < 2; ++kk)
    qf[kk] = *(const short8*)(base + (size_t)(s0 + wid*16 + fr) * QKV_N + kk*32 + fg*8);
  f32x4 o[4] = {};
  float Mr[4], Lr[4];
  #pragma unroll
  for (int r = 0; r < 4; ++r) { Mr[r] = -1e30f; Lr[r] = 0.f; }
  const float CSC = 0.125f * 1.44269504f;  // SCALE * log2(e)
  for (int c0 = 0; c0 < SEQ; c0 += 64) {
    // --- stage K: linear LDS dest, inverse-swizzled per-lane global src ---
    #pragma unroll
    for (int p = 0; p < 2; ++p) {
      int W = p*4 + wid;
      int row = W*8 + (lane >> 3);
      int g = (lane & 7) ^ W ^ (lane >> 3);   // sc ^ S(row)
      gload_lds16(base + (size_t)(c0 + row)*QKV_N + 64 + g*8,
                  Ks + (W*64 + lane)*8);
    }
    // --- stage V transposed; chunk swizzled by S(h) = (h>>3)^(h&7) ---
    #pragma unroll
    for (int it = 0; it < 2; ++it) {
      int key = it*32 + (tid >> 3);
      int h0b = tid & 7;                       // h>>3 for this thread
      int kc = key >> 3, ko = key & 7;
      union { short8 v; bf16 hh[8]; } u;
      u.v = *(const short8*)(base + (size_t)(c0 + key)*QKV_N + 128 + h0b*8);
      #pragma unroll
      for (int j = 0; j < 8; ++j) {
        int sc = kc ^ h0b ^ j;
        VTs[(h0b*8 + j)*64 + sc*8 + ko] = u.hh[j];
      }
    }
    __syncthreads();
    // --- QK^T ---
    f32x4 sc4[4] = {};
    #pragma unroll
    for (int kk = 0; kk < 2; ++kk) {
      #pragma unroll
      for (int ni = 0; ni < 4; ++ni) {
        int S = (ni*2 + (fr >> 3)) ^ (fr & 7);
        int c = (kk*4 + fg) ^ S;
        short8 kf = *(const short8*)(Ks + (ni*16 + fr)*64 + c*8);
        sc4[ni] = __builtin_amdgcn_mfma_f32_16x16x32_bf16(qf[kk], kf, sc4[ni], 0, 0, 0);
      }
    }
    // --- online softmax ---
    float Pf[4][4];
    #pragma unroll
    for (int r = 0; r < 4; ++r) {
      float mx = fmaxf(fmaxf(sc4[0][r], sc4[1][r]), fmaxf(sc4[2][r], sc4[3][r])) * CSC;
      #pragma unroll
      for (int m = 8; m >= 1; m >>= 1) mx = fmaxf(mx, __shfl_xor(mx, m));
      float Mn = fmaxf(Mr[r], mx);
      float so = exp2f(Mr[r] - Mn);
      Mr[r] = Mn;
      float ls = 0.f;
      #pragma unroll
      for (int ni = 0; ni < 4; ++ni) {
        float p = exp2f(sc4[ni][r] * CSC - Mn);
        Pf[ni][r] = p; ls += p;
      }
      #pragma unroll
      for (int m = 8; m >= 1; m >>= 1) ls += __shfl_xor(ls, m);
      Lr[r] = Lr[r] * so + ls;
      #pragma unroll
      for (int hi = 0; hi < 4; ++hi) o[hi][r] *= so;
    }
    // --- P via padded LDS ---
    #pragma unroll
    for (int r = 0; r < 4; ++r) {
      #pragma unroll
      for (int ni = 0; ni < 4; ++ni)
        Ps[wid][(fg*4 + r)*PS_LD + ni*16 + fr] = __float2bfloat16(Pf[ni][r]);
    }
    // --- PV ---
    #pragma unroll
    for (int kk = 0; kk < 2; ++kk) {
      short8 pf = *(const short8*)(&Ps[wid][fr*PS_LD + kk*32 + fg*8]);
      #pragma unroll
      for (int hi = 0; hi < 4; ++hi) {
        int S = (hi*2 + (fr >> 3)) ^ (fr & 7);
        int c = (kk*4 + fg) ^ S;
        short8 vf = *(const short8*)(VTs + (hi*16 + fr)*64 + c*8);
        o[hi] = __builtin_amdgcn_mfma_f32_16x16x32_bf16(pf, vf, o[hi], 0, 0, 0);
      }
    }
    __syncthreads();
  }
  const int rowb = b * SEQ + s0 + wid*16 + fg*4;
  #pragma unroll
  for (int r = 0; r < 4; ++r) {
    const float g = gates[(size_t)(rowb + r) * NUM_EXPERTS + e];
    const float inv = g / Lr[r];
    #pragma unroll
    for (int hi = 0; hi < 4; ++hi)
      combined[(size_t)(rowb + r) * D_MODEL + e*64 + hi*16 + fr] =
          __float2bfloat16(o[hi][r] * inv);
  }
}

extern "C" void kernel_launch(void* const* d_in, const int* in_sizes, int n_in,
                              void* d_out, int out_size, void* d_ws, size_t ws_size,
                              hipStream_t stream) {
  const float* x    = (const float*)d_in[0];
  const float* wqkv = (const float*)d_in[1];
  const float* bqkv = (const float*)d_in[2];
  const float* rw   = (const float*)d_in[3];
  const float* rb   = (const float*)d_in[4];
  const float* ow   = (const float*)d_in[5];
  const float* ob   = (const float*)d_in[6];
  char* ws = (char*)d_ws;
  bf16*  xb    = (bf16*)(ws);                    // 4096*1280*2      = 10485760
  bf16*  wqkvT = (bf16*)(ws + 10485760);         // 20*192*1280*2    =  9830400
  bf16*  owT   = (bf16*)(ws + 20316160);         // 1280*1280*2      =  3276800
  float* gates = (float*)(ws + 23592960);        // 4096*20*4        =   327680
  bf16*  qkv   = (bf16*)(ws + 23920640);         // 20*4096*192*2    = 31457280
  bf16*  comb  = (bf16*)(ws + 55377920);         // 4096*1280*2      = 10485760
  float* rwT   = (float*)comb;                   // aliased, consumed pre-attn

  k_rwT<<<(D_MODEL * NUM_EXPERTS + 255) / 256, 256, 0, stream>>>(rw, rwT);
  k_gates<<<1024, 256, 0, stream>>>(x, rwT, rb, gates, xb);
  k_transpose<<<dim3(6, 40, 20), dim3(32, 8), 0, stream>>>(wqkv, wqkvT, D_MODEL, QKV_N);
  k_transpose<<<dim3(40, 40, 1), dim3(32, 8), 0, stream>>>(ow, owT, D_MODEL, D_MODEL);
  k_gemm<true><<<dim3(32, 3, 20), 256, 0, stream>>>(xb, wqkvT, bqkv, qkv,
                                                    BS_TOK, QKV_N, D_MODEL);
  k_attn<<<1280, 256, 0, stream>>>(qkv, gates, comb);
  k_gemm<false><<<dim3(32, 20, 1), 256, 0, stream>>>(comb, owT, ob, d_out,
                                                     BS_TOK, D_MODEL, D_MODEL);
}